// Round 18
// baseline (271.884 us; speedup 1.0000x reference)
//
#include <hip/hip_runtime.h>
#include <hip/hip_bf16.h>

typedef __bf16 bf16;
typedef __bf16 bf16x2 __attribute__((ext_vector_type(2)));
typedef __bf16 bf16x4 __attribute__((ext_vector_type(4)));
typedef __bf16 bf16x8 __attribute__((ext_vector_type(8)));
typedef float f32x4 __attribute__((ext_vector_type(4)));

#define B_ 32
#define S_ 512
#define D_ 1024
#define H_ 16
#define DH_ 64
#define M_ (B_*S_)   // 16384

#if __has_builtin(__builtin_amdgcn_exp2f)
#define FEXP2 __builtin_amdgcn_exp2f
#else
#define FEXP2 exp2f
#endif

__device__ __forceinline__ void async16(const void* g, void* l) {
  __builtin_amdgcn_global_load_lds(
      (const __attribute__((address_space(1))) unsigned int*)g,
      (__attribute__((address_space(3))) unsigned int*)l, 16, 0, 0);
}

// ---------------- LayerNorm + bf16 cast (both tensors in one launch) ----------
__global__ __launch_bounds__(256) void ln_bf16(
    const float* __restrict__ qk, const float* __restrict__ v,
    const float* __restrict__ g1, const float* __restrict__ b1,
    const float* __restrict__ g2, const float* __restrict__ b2,
    bf16* __restrict__ o1, bf16* __restrict__ o2)
{
  int row = blockIdx.x;
  const float* src; const float* g; const float* b; bf16* o; int r;
  if (row < M_) { src=qk; g=g1; b=b1; o=o1; r=row; }
  else          { src=v;  g=g2; b=b2; o=o2; r=row-M_; }
  int t = threadIdx.x;
  float4 x = ((const float4*)(src + (size_t)r*D_))[t];
  float s  = x.x+x.y+x.z+x.w;
  float ss = x.x*x.x + x.y*x.y + x.z*x.z + x.w*x.w;
  #pragma unroll
  for (int off=32; off>=1; off>>=1) {
    s  += __shfl_xor(s,  off, 64);
    ss += __shfl_xor(ss, off, 64);
  }
  __shared__ float red[8];
  int w = t>>6, l = t&63;
  if (l==0){ red[w]=s; red[4+w]=ss; }
  __syncthreads();
  s  = red[0]+red[1]+red[2]+red[3];
  ss = red[4]+red[5]+red[6]+red[7];
  float mu  = s*(1.f/D_);
  float var = ss*(1.f/D_) - mu*mu;
  float rs  = rsqrtf(var + 1e-5f);
  float4 gg = ((const float4*)g)[t];
  float4 bb = ((const float4*)b)[t];
  bf16x4 ov;
  ov[0] = (bf16)((x.x-mu)*rs*gg.x + bb.x);
  ov[1] = (bf16)((x.y-mu)*rs*gg.y + bb.y);
  ov[2] = (bf16)((x.z-mu)*rs*gg.z + bb.z);
  ov[3] = (bf16)((x.w-mu)*rs*gg.w + bb.w);
  ((bf16x4*)(o + (size_t)r*D_))[t] = ov;
}

// ---------------- Weight transpose + bf16 cast: Wt[N][K] = W[K][N] ------------
__global__ void wtrans(const float* __restrict__ W0, const float* __restrict__ W1,
                       const float* __restrict__ W2, const float* __restrict__ W3,
                       bf16* __restrict__ o0, bf16* __restrict__ o1,
                       bf16* __restrict__ o2, bf16* __restrict__ o3)
{
  int z = blockIdx.z;
  const float* W = z==0?W0: z==1?W1: z==2?W2: W3;
  bf16* o        = z==0?o0: z==1?o1: z==2?o2: o3;
  __shared__ float tile[32][33];
  int n0 = blockIdx.x*32, k0 = blockIdx.y*32;
  int tx = threadIdx.x, ty = threadIdx.y;   // block (32,8)
  #pragma unroll
  for (int i=0;i<4;i++) tile[ty + i*8][tx] = W[(size_t)(k0+ty+i*8)*D_ + n0+tx];
  __syncthreads();
  #pragma unroll
  for (int i=0;i<4;i++) o[(size_t)(n0+ty+i*8)*D_ + k0+tx] = (bf16)tile[tx][ty+i*8];
}

// ---------------- GEMM: C[M,N] = A[M,K] * Bt[N,K]^T + bias -------------------
// 128x128 tile, BK=64, dbuf LDS, depth-2 prefetch, counted vmcnt, setprio, XOR
// swizzle. (Round-10/16 config: 892 TF — the 128²-structure ceiling. 256²
// abandoned: 3 schedules all spill on this toolchain's allocator.)
// MODE 0: N=2048, split outputs (Q | K), bf16 row-major
// MODE 1: N=1024, V fragment-image out (VF): zero-shuffle PV layout
// MODE 2: N=1024, f32 out + residual
template<int MODE>
__global__ __launch_bounds__(256) void gemm_bt(
    const bf16* __restrict__ A, const bf16* __restrict__ Bt,
    const float* __restrict__ bias0, const float* __restrict__ bias1,
    const bf16* __restrict__ res,
    bf16* __restrict__ out0, bf16* __restrict__ out1, float* __restrict__ outf)
{
  __shared__ bf16 A_sh[2][128*64];
  __shared__ bf16 B_sh[2][128*64];
  int t = threadIdx.x;
  int nwg  = gridDim.x * gridDim.y;
  int orig = blockIdx.y * gridDim.x + blockIdx.x;
  int qch  = nwg >> 3;
  int wg   = (orig & 7) * qch + (orig >> 3);
  int bx = wg % gridDim.x, by = wg / gridDim.x;
  int n0 = bx*128, m0 = by*128;
  int w = t>>6, l = t&63, lr = l&15, lg = (l>>4)&3;
  int wm = w>>1, wn = w&1;

  auto stage = [&](int buf, int kt){
    const bf16* Ab = A  + (size_t)m0*D_ + kt*64;
    const bf16* Bb = Bt + (size_t)n0*D_ + kt*64;
    #pragma unroll
    for (int i=0;i<4;i++){
      int c = i*256 + t;
      int row = c>>3, slot = (c&7) ^ (row&7);
      async16(Ab + (size_t)row*D_ + slot*8, &A_sh[buf][c*8]);
      async16(Bb + (size_t)row*D_ + slot*8, &B_sh[buf][c*8]);
    }
  };

  f32x4 acc[4][4];
  #pragma unroll
  for (int m=0;m<4;m++)
    #pragma unroll
    for (int n=0;n<4;n++) acc[m][n] = (f32x4){0.f,0.f,0.f,0.f};

  stage(0, 0);
  stage(1, 1);
  asm volatile("s_waitcnt vmcnt(8)" ::: "memory");   // tile 0 landed, tile 1 in flight
  __builtin_amdgcn_s_barrier();

  for (int kt=0; kt<16; ++kt) {
    int cur = kt & 1;
    bf16x8 af[4][2], bfr[4][2];
    #pragma unroll
    for (int m=0;m<4;m++){
      int row = wm*64 + m*16 + lr;
      #pragma unroll
      for (int kk=0;kk<2;kk++)
        af[m][kk] = *(const bf16x8*)&A_sh[cur][row*64 + (((kk*4+lg)^(lr&7))*8)];
    }
    #pragma unroll
    for (int n=0;n<4;n++){
      int row = wn*64 + n*16 + lr;
      #pragma unroll
      for (int kk=0;kk<2;kk++)
        bfr[n][kk] = *(const bf16x8*)&B_sh[cur][row*64 + (((kk*4+lg)^(lr&7))*8)];
    }
    asm volatile("s_waitcnt lgkmcnt(0)" ::: "memory"); // my reads complete
    __builtin_amdgcn_sched_barrier(0);
    __builtin_amdgcn_s_barrier();                      // all waves' reads complete
    if (kt+2 < 16) stage(cur, kt+2);                   // recycle buffer
    __builtin_amdgcn_s_setprio(1);
    #pragma unroll
    for (int kk=0;kk<2;kk++)
      #pragma unroll
      for (int m=0;m<4;m++)
        #pragma unroll
        for (int n=0;n<4;n++)
          acc[m][n] = __builtin_amdgcn_mfma_f32_16x16x32_bf16(af[m][kk], bfr[n][kk], acc[m][n], 0,0,0);
    __builtin_amdgcn_s_setprio(0);
    if (kt < 14)       asm volatile("s_waitcnt vmcnt(8)" ::: "memory");
    else if (kt == 14) asm volatile("s_waitcnt vmcnt(0)" ::: "memory");
    if (kt < 15) { __builtin_amdgcn_sched_barrier(0); __builtin_amdgcn_s_barrier(); }
  }

  if (MODE == 0) {
    #pragma unroll
    for (int n=0;n<4;n++){
      int col = n0 + wn*64 + n*16 + lr;
      bf16* dst; int c;
      if (col < D_) { dst = out0; c = col; } else { dst = out1; c = col - D_; }
      float bv = (col < D_) ? bias0[c] : bias1[c];
      #pragma unroll
      for (int m=0;m<4;m++){
        #pragma unroll
        for (int j=0;j<4;j++){
          size_t row = (size_t)m0 + wm*64 + m*16 + lg*4 + j;
          dst[row*D_ + c] = (bf16)(acc[m][n][j] + bv);
        }
      }
    }
  } else if (MODE == 1) {
    // VF fragment-image: granule = 4 consecutive s (j=0..3) at fixed dh.
    #pragma unroll
    for (int n=0;n<4;n++){
      int col = n0 + wn*64 + n*16 + lr;       // h*64 + dh
      int hh = col >> 6, dh = col & 63;
      int nd = dh >> 4, lrk = dh & 15;
      float bv = bias0[col];
      #pragma unroll
      for (int m=0;m<4;m++){
        int row = m0 + wm*64 + m*16 + lg*4;   // s base of granule
        int bb = row >> 9, sl = row & 511;
        int kt = sl >> 6, l0 = sl & 63;
        int kk = (l0>>5)&1, h8 = (l0>>4)&1, lgk = (l0>>2)&3;
        int c  = ((nd*2+kk)*4+lgk)*16 + lrk;
        bf16x4 pk4;
        #pragma unroll
        for (int j=0;j<4;j++) pk4[j] = (bf16)(acc[m][n][j] + bv);
        *(bf16x4*)&out0[(size_t)(((bb*H_ + hh)*8 + kt)*4096) + c*8 + h8*4] = pk4;
      }
    }
  } else {
    #pragma unroll
    for (int m=0;m<4;m++){
      #pragma unroll
      for (int j=0;j<4;j++){
        size_t row = (size_t)m0 + wm*64 + m*16 + lg*4 + j;
        #pragma unroll
        for (int n=0;n<4;n++){
          int col = n0 + wn*64 + n*16 + lr;
          size_t idx = row*D_ + col;
          outf[idx] = acc[m][n][j] + bias0[col] + (float)res[idx];
        }
      }
    }
  }
}

// ---------------- Flash attention: ring-3 KV, ONE barrier per tile -----------
// K: [b][s][h][dh]; VF: fragment-image. Grid (2,16,32), 512 thr, 8 waves.
// Zero-shuffle PV. Ring-3 staging: top-of-iter prefetch of tile kt+2 into slot
// (kt+2)%3 (never the slot being read); slot kt%3 is only overwritten at iter
// kt+1's top-stage, which is issued after iter kt's lgkm(0)+barrier. vmcnt(2)
// at iter end => tile kt+1 landed. Halves barrier count vs dbuf-2.
__global__ __launch_bounds__(512) void attn_fwd(
    const bf16* __restrict__ Q, const bf16* __restrict__ K,
    const bf16* __restrict__ VF, const int* __restrict__ mask,
    bf16* __restrict__ ctx)
{
  int flat = blockIdx.x + (blockIdx.y<<1) + (blockIdx.z<<5);   // 1024 wgs
  int work = (flat & 7)*128 + (flat >> 3);                     // bijective (1024%8==0)
  int qt = work & 1, h = (work>>1) & 15, b = work >> 5;
  int q0 = qt*256;
  int t = threadIdx.x, w = t>>6, l = t&63, lr = l&15, lg = (l>>4)&3;

  __shared__ bf16 K_s[3][4096];
  __shared__ bf16 V_s[3][4096];
  __shared__ float msk[512];

  const float SC = 0.125f * 1.44269504f;
  msk[t] = mask[b*S_+t] ? 0.f : -1.44269504e9f;

  size_t qbase  = ((size_t)(b*S_ + q0)*H_ + h)*DH_;
  size_t vfbase = (size_t)(b*H_ + h)*8*4096;

  auto stageKV = [&](int slot, int kt){
    size_t kb = ((size_t)(b*S_ + kt*64)*H_ + h)*DH_;
    int clr=t&15, clg=(t>>4)&3, ckk=(t>>6)&1, n16=t>>7;   // t = 0..511 chunks
    async16(K + kb + (size_t)(n16*16+clr)*D_ + ckk*32 + clg*8, &K_s[slot][t*8]);
    async16(VF + vfbase + (size_t)kt*4096 + t*8, &V_s[slot][t*8]);  // linear!
  };

  // Q straight to registers; wave w owns q rows w*32 .. w*32+31
  bf16x8 qa[2][2];
  #pragma unroll
  for (int s=0;s<2;s++)
    #pragma unroll
    for (int kk=0;kk<2;kk++)
      qa[s][kk] = *(const bf16x8*)(Q + qbase + (size_t)(w*32 + s*16 + lr)*D_ + kk*32 + lg*8);

  stageKV(0, 0);
  stageKV(1, 1);
  asm volatile("s_waitcnt vmcnt(2) lgkmcnt(0)" ::: "memory"); // Q + tile0 done, tile1 in flight
  __builtin_amdgcn_s_barrier();

  f32x4 cacc[2][4];
  #pragma unroll
  for (int s=0;s<2;s++)
    #pragma unroll
    for (int n=0;n<4;n++) cacc[s][n] = (f32x4){0.f,0.f,0.f,0.f};
  float mrun[2] = {-3.0e38f, -3.0e38f};
  float lrun[2] = {0.f, 0.f};

  union UPA { unsigned u[4]; bf16x8 v; };
  UPA pa[2][2];

  for (int kt=0; kt<8; ++kt) {
    int cur = kt % 3;
    const bf16* Ks = K_s[cur];
    const bf16* Vs = V_s[cur];
    if (kt+2 < 8) stageKV((kt+2)%3, kt+2);   // top-of-iter prefetch

    // K fragments read ONCE, feed both q-subtiles
    bf16x8 kf[4][2];
    #pragma unroll
    for (int n=0;n<4;n++)
      #pragma unroll
      for (int kk=0;kk<2;kk++)
        kf[n][kk] = *(const bf16x8*)&Ks[(((n*2+kk)*4+lg)*16+lr)*8];

    // mask hoisted out of the s-loop (same for both q-subtiles)
    float4 mk[4];
    #pragma unroll
    for (int n=0;n<4;n++) mk[n] = *(const float4*)&msk[kt*64 + n*16 + lg*4];

    #pragma unroll
    for (int s=0;s<2;s++){
      float p[4][4];
      #pragma unroll
      for (int n=0;n<4;n++){
        f32x4 sa = (f32x4){0.f,0.f,0.f,0.f};
        #pragma unroll
        for (int kk=0;kk<2;kk++)
          sa = __builtin_amdgcn_mfma_f32_16x16x32_bf16(kf[n][kk], qa[s][kk], sa, 0,0,0);
        p[n][0] = sa[0]*SC + mk[n].x;
        p[n][1] = sa[1]*SC + mk[n].y;
        p[n][2] = sa[2]*SC + mk[n].z;
        p[n][3] = sa[3]*SC + mk[n].w;
      }

      float pm = fmaxf(fmaxf(p[0][0],p[0][1]),fmaxf(p[0][2],p[0][3]));
      #pragma unroll
      for (int n=1;n<4;n++)
        pm = fmaxf(pm, fmaxf(fmaxf(p[n][0],p[n][1]),fmaxf(p[n][2],p[n][3])));
      pm = fmaxf(pm, __shfl_xor(pm, 16, 64));
      pm = fmaxf(pm, __shfl_xor(pm, 32, 64));

      if (__any((int)(pm - mrun[s] > 8.f))) {          // T13 defer-max
        float mnew  = fmaxf(mrun[s], pm);
        float alpha = FEXP2(mrun[s] - mnew);
        mrun[s] = mnew;
        lrun[s] *= alpha;
        #pragma unroll
        for (int n=0;n<4;n++) cacc[s][n] *= alpha;
      }
      float ps = 0.f;
      #pragma unroll
      for (int n=0;n<4;n++)
        #pragma unroll
        for (int j=0;j<4;j++){ p[n][j] = FEXP2(p[n][j] - mrun[s]); ps += p[n][j]; }
      ps += __shfl_xor(ps, 16, 64);
      ps += __shfl_xor(ps, 32, 64);
      lrun[s] += ps;

      // pack P -> bf16 pairs; pa = in-lane rename (NO shuffles)
      unsigned pk[4][2];
      #pragma unroll
      for (int n=0;n<4;n++)
        #pragma unroll
        for (int i=0;i<2;i++){
          union { bf16x2 v; unsigned u; } u2;
          u2.v[0] = (bf16)p[n][2*i];
          u2.v[1] = (bf16)p[n][2*i+1];
          pk[n][i] = u2.u;
        }
      #pragma unroll
      for (int kk=0;kk<2;kk++){
        pa[s][kk].u[0] = pk[2*kk  ][0];
        pa[s][kk].u[1] = pk[2*kk  ][1];
        pa[s][kk].u[2] = pk[2*kk+1][0];
        pa[s][kk].u[3] = pk[2*kk+1][1];
      }
    }

    // PV: V fragments read inline from slot cur
    __builtin_amdgcn_s_setprio(1);
    #pragma unroll
    for (int nd=0;nd<4;nd++){
      bf16x8 vb0 = *(const bf16x8*)&Vs[(((nd*2+0)*4+lg)*16+lr)*8];
      bf16x8 vb1 = *(const bf16x8*)&Vs[(((nd*2+1)*4+lg)*16+lr)*8];
      #pragma unroll
      for (int s=0;s<2;s++){
        cacc[s][nd] = __builtin_amdgcn_mfma_f32_16x16x32_bf16(vb0, pa[s][0].v, cacc[s][nd], 0,0,0);
        cacc[s][nd] = __builtin_amdgcn_mfma_f32_16x16x32_bf16(vb1, pa[s][1].v, cacc[s][nd], 0,0,0);
      }
    }
    __builtin_amdgcn_s_setprio(0);

    asm volatile("s_waitcnt lgkmcnt(0)" ::: "memory");  // my reads of slot cur done
    if (kt < 6)       asm volatile("s_waitcnt vmcnt(2)" ::: "memory");  // tile kt+1 landed
    else if (kt == 6) asm volatile("s_waitcnt vmcnt(0)" ::: "memory");
    if (kt < 7) { __builtin_amdgcn_sched_barrier(0); __builtin_amdgcn_s_barrier(); }
  }

  #pragma unroll
  for (int s=0;s<2;s++){
    float rl = 1.0f / lrun[s];
    size_t obase = qbase + (size_t)(w*32 + s*16 + lr)*D_;
    #pragma unroll
    for (int nd=0;nd<4;nd++){
      bf16x4 o4;
      #pragma unroll
      for (int j=0;j<4;j++) o4[j] = (bf16)(cacc[s][nd][j]*rl);
      *(bf16x4*)&ctx[obase + nd*16 + lg*4] = o4;
    }
  }
}

// ------------------------------ launcher --------------------------------------
extern "C" void kernel_launch(void* const* d_in, const int* in_sizes, int n_in,
                              void* d_out, int out_size, void* d_ws, size_t ws_size,
                              hipStream_t stream)
{
  (void)in_sizes; (void)n_in; (void)out_size; (void)ws_size;
  const float* qk   = (const float*)d_in[0];
  const float* v    = (const float*)d_in[1];
  const int*   mask = (const int*)  d_in[2];
  const float* qk_g = (const float*)d_in[3];
  const float* qk_b = (const float*)d_in[4];
  const float* v_g  = (const float*)d_in[5];
  const float* v_b  = (const float*)d_in[6];
  const float* Wq   = (const float*)d_in[7];
  const float* bq   = (const float*)d_in[8];
  const float* Wk   = (const float*)d_in[9];
  const float* bk   = (const float*)d_in[10];
  const float* Wv   = (const float*)d_in[11];
  const float* bv   = (const float*)d_in[12];
  const float* Wo   = (const float*)d_in[13];
  const float* bo   = (const float*)d_in[14];
  float* out = (float*)d_out;

  char* ws = (char*)d_ws;
  size_t off = 0;
  auto alloc = [&](size_t bytes){ void* p = ws + off; off += (bytes + 255) & ~(size_t)255; return p; };
  bf16* qkn  = (bf16*)alloc((size_t)M_*D_*2);
  bf16* vn   = (bf16*)alloc((size_t)M_*D_*2);
  bf16* Qb   = (bf16*)alloc((size_t)M_*D_*2);
  bf16* Kb   = (bf16*)alloc((size_t)M_*D_*2);
  bf16* VFb  = (bf16*)alloc((size_t)M_*D_*2);   // V fragment-image
  bf16* Cb   = (bf16*)alloc((size_t)M_*D_*2);
  bf16* WqkT = (bf16*)alloc((size_t)2*D_*D_*2);
  bf16* WvT  = (bf16*)alloc((size_t)D_*D_*2);
  bf16* WoT  = (bf16*)alloc((size_t)D_*D_*2);

  ln_bf16<<<2*M_, 256, 0, stream>>>(qk, v, qk_g, qk_b, v_g, v_b, qkn, vn);
  wtrans<<<dim3(32,32,4), dim3(32,8), 0, stream>>>(Wq, Wk, Wv, Wo,
      WqkT, WqkT + (size_t)D_*D_, WvT, WoT);
  gemm_bt<0><<<dim3(16,128), 256, 0, stream>>>(qkn, WqkT, bq, bk, nullptr, Qb, Kb, nullptr);
  gemm_bt<1><<<dim3(8,128),  256, 0, stream>>>(vn,  WvT,  bv, nullptr, nullptr, VFb, nullptr, nullptr);
  attn_fwd<<<dim3(2, 16, 32), 512, 0, stream>>>(Qb, Kb, VFb, mask, Cb);
  gemm_bt<2><<<dim3(8,128),  256, 0, stream>>>(Cb, WoT, bo, nullptr, vn, nullptr, nullptr, out);
}

// Round 19
// 257.076 us; speedup vs baseline: 1.0576x; 1.0576x over previous
//
#include <hip/hip_runtime.h>
#include <hip/hip_bf16.h>

typedef __bf16 bf16;
typedef __bf16 bf16x2 __attribute__((ext_vector_type(2)));
typedef __bf16 bf16x4 __attribute__((ext_vector_type(4)));
typedef __bf16 bf16x8 __attribute__((ext_vector_type(8)));
typedef float f32x4 __attribute__((ext_vector_type(4)));

#define B_ 32
#define S_ 512
#define D_ 1024
#define H_ 16
#define DH_ 64
#define M_ (B_*S_)   // 16384

#if __has_builtin(__builtin_amdgcn_exp2f)
#define FEXP2 __builtin_amdgcn_exp2f
#else
#define FEXP2 exp2f
#endif

__device__ __forceinline__ void async16(const void* g, void* l) {
  __builtin_amdgcn_global_load_lds(
      (const __attribute__((address_space(1))) unsigned int*)g,
      (__attribute__((address_space(3))) unsigned int*)l, 16, 0, 0);
}

// ---------------- LayerNorm + bf16 cast (both tensors in one launch) ----------
__global__ __launch_bounds__(256) void ln_bf16(
    const float* __restrict__ qk, const float* __restrict__ v,
    const float* __restrict__ g1, const float* __restrict__ b1,
    const float* __restrict__ g2, const float* __restrict__ b2,
    bf16* __restrict__ o1, bf16* __restrict__ o2)
{
  int row = blockIdx.x;
  const float* src; const float* g; const float* b; bf16* o; int r;
  if (row < M_) { src=qk; g=g1; b=b1; o=o1; r=row; }
  else          { src=v;  g=g2; b=b2; o=o2; r=row-M_; }
  int t = threadIdx.x;
  float4 x = ((const float4*)(src + (size_t)r*D_))[t];
  float s  = x.x+x.y+x.z+x.w;
  float ss = x.x*x.x + x.y*x.y + x.z*x.z + x.w*x.w;
  #pragma unroll
  for (int off=32; off>=1; off>>=1) {
    s  += __shfl_xor(s,  off, 64);
    ss += __shfl_xor(ss, off, 64);
  }
  __shared__ float red[8];
  int w = t>>6, l = t&63;
  if (l==0){ red[w]=s; red[4+w]=ss; }
  __syncthreads();
  s  = red[0]+red[1]+red[2]+red[3];
  ss = red[4]+red[5]+red[6]+red[7];
  float mu  = s*(1.f/D_);
  float var = ss*(1.f/D_) - mu*mu;
  float rs  = rsqrtf(var + 1e-5f);
  float4 gg = ((const float4*)g)[t];
  float4 bb = ((const float4*)b)[t];
  bf16x4 ov;
  ov[0] = (bf16)((x.x-mu)*rs*gg.x + bb.x);
  ov[1] = (bf16)((x.y-mu)*rs*gg.y + bb.y);
  ov[2] = (bf16)((x.z-mu)*rs*gg.z + bb.z);
  ov[3] = (bf16)((x.w-mu)*rs*gg.w + bb.w);
  ((bf16x4*)(o + (size_t)r*D_))[t] = ov;
}

// ---------------- Weight transpose + bf16 cast: Wt[N][K] = W[K][N] ------------
__global__ void wtrans(const float* __restrict__ W0, const float* __restrict__ W1,
                       const float* __restrict__ W2, const float* __restrict__ W3,
                       bf16* __restrict__ o0, bf16* __restrict__ o1,
                       bf16* __restrict__ o2, bf16* __restrict__ o3)
{
  int z = blockIdx.z;
  const float* W = z==0?W0: z==1?W1: z==2?W2: W3;
  bf16* o        = z==0?o0: z==1?o1: z==2?o2: o3;
  __shared__ float tile[32][33];
  int n0 = blockIdx.x*32, k0 = blockIdx.y*32;
  int tx = threadIdx.x, ty = threadIdx.y;   // block (32,8)
  #pragma unroll
  for (int i=0;i<4;i++) tile[ty + i*8][tx] = W[(size_t)(k0+ty+i*8)*D_ + n0+tx];
  __syncthreads();
  #pragma unroll
  for (int i=0;i<4;i++) o[(size_t)(n0+ty+i*8)*D_ + k0+tx] = (bf16)tile[tx][ty+i*8];
}

// ---------------- GEMM: C[M,N] = A[M,K] * Bt[N,K]^T + bias -------------------
// 128x128 tile, BK=64, dbuf LDS, depth-2 prefetch, counted vmcnt, setprio, XOR
// swizzle. (892 TF — the 128²-structure ceiling on this toolchain.)
// MODE 0: N=2048, split outputs (Q | K), bf16 row-major
// MODE 1: N=1024, V fragment-image out (VF): zero-shuffle PV layout
// MODE 2: N=1024, f32 out + residual
template<int MODE>
__global__ __launch_bounds__(256) void gemm_bt(
    const bf16* __restrict__ A, const bf16* __restrict__ Bt,
    const float* __restrict__ bias0, const float* __restrict__ bias1,
    const bf16* __restrict__ res,
    bf16* __restrict__ out0, bf16* __restrict__ out1, float* __restrict__ outf)
{
  __shared__ bf16 A_sh[2][128*64];
  __shared__ bf16 B_sh[2][128*64];
  int t = threadIdx.x;
  int nwg  = gridDim.x * gridDim.y;
  int orig = blockIdx.y * gridDim.x + blockIdx.x;
  int qch  = nwg >> 3;
  int wg   = (orig & 7) * qch + (orig >> 3);
  int bx = wg % gridDim.x, by = wg / gridDim.x;
  int n0 = bx*128, m0 = by*128;
  int w = t>>6, l = t&63, lr = l&15, lg = (l>>4)&3;
  int wm = w>>1, wn = w&1;

  auto stage = [&](int buf, int kt){
    const bf16* Ab = A  + (size_t)m0*D_ + kt*64;
    const bf16* Bb = Bt + (size_t)n0*D_ + kt*64;
    #pragma unroll
    for (int i=0;i<4;i++){
      int c = i*256 + t;
      int row = c>>3, slot = (c&7) ^ (row&7);
      async16(Ab + (size_t)row*D_ + slot*8, &A_sh[buf][c*8]);
      async16(Bb + (size_t)row*D_ + slot*8, &B_sh[buf][c*8]);
    }
  };

  f32x4 acc[4][4];
  #pragma unroll
  for (int m=0;m<4;m++)
    #pragma unroll
    for (int n=0;n<4;n++) acc[m][n] = (f32x4){0.f,0.f,0.f,0.f};

  stage(0, 0);
  stage(1, 1);
  asm volatile("s_waitcnt vmcnt(8)" ::: "memory");   // tile 0 landed, tile 1 in flight
  __builtin_amdgcn_s_barrier();

  for (int kt=0; kt<16; ++kt) {
    int cur = kt & 1;
    bf16x8 af[4][2], bfr[4][2];
    #pragma unroll
    for (int m=0;m<4;m++){
      int row = wm*64 + m*16 + lr;
      #pragma unroll
      for (int kk=0;kk<2;kk++)
        af[m][kk] = *(const bf16x8*)&A_sh[cur][row*64 + (((kk*4+lg)^(lr&7))*8)];
    }
    #pragma unroll
    for (int n=0;n<4;n++){
      int row = wn*64 + n*16 + lr;
      #pragma unroll
      for (int kk=0;kk<2;kk++)
        bfr[n][kk] = *(const bf16x8*)&B_sh[cur][row*64 + (((kk*4+lg)^(lr&7))*8)];
    }
    asm volatile("s_waitcnt lgkmcnt(0)" ::: "memory"); // my reads complete
    __builtin_amdgcn_sched_barrier(0);
    __builtin_amdgcn_s_barrier();                      // all waves' reads complete
    if (kt+2 < 16) stage(cur, kt+2);                   // recycle buffer
    __builtin_amdgcn_s_setprio(1);
    #pragma unroll
    for (int kk=0;kk<2;kk++)
      #pragma unroll
      for (int m=0;m<4;m++)
        #pragma unroll
        for (int n=0;n<4;n++)
          acc[m][n] = __builtin_amdgcn_mfma_f32_16x16x32_bf16(af[m][kk], bfr[n][kk], acc[m][n], 0,0,0);
    __builtin_amdgcn_s_setprio(0);
    if (kt < 14)       asm volatile("s_waitcnt vmcnt(8)" ::: "memory");
    else if (kt == 14) asm volatile("s_waitcnt vmcnt(0)" ::: "memory");
    if (kt < 15) { __builtin_amdgcn_sched_barrier(0); __builtin_amdgcn_s_barrier(); }
  }

  if (MODE == 0) {
    #pragma unroll
    for (int n=0;n<4;n++){
      int col = n0 + wn*64 + n*16 + lr;
      bf16* dst; int c;
      if (col < D_) { dst = out0; c = col; } else { dst = out1; c = col - D_; }
      float bv = (col < D_) ? bias0[c] : bias1[c];
      #pragma unroll
      for (int m=0;m<4;m++){
        #pragma unroll
        for (int j=0;j<4;j++){
          size_t row = (size_t)m0 + wm*64 + m*16 + lg*4 + j;
          dst[row*D_ + c] = (bf16)(acc[m][n][j] + bv);
        }
      }
    }
  } else if (MODE == 1) {
    // VF fragment-image: granule = 4 consecutive s (j=0..3) at fixed dh.
    #pragma unroll
    for (int n=0;n<4;n++){
      int col = n0 + wn*64 + n*16 + lr;       // h*64 + dh
      int hh = col >> 6, dh = col & 63;
      int nd = dh >> 4, lrk = dh & 15;
      float bv = bias0[col];
      #pragma unroll
      for (int m=0;m<4;m++){
        int row = m0 + wm*64 + m*16 + lg*4;   // s base of granule
        int bb = row >> 9, sl = row & 511;
        int kt = sl >> 6, l0 = sl & 63;
        int kk = (l0>>5)&1, h8 = (l0>>4)&1, lgk = (l0>>2)&3;
        int c  = ((nd*2+kk)*4+lgk)*16 + lrk;
        bf16x4 pk4;
        #pragma unroll
        for (int j=0;j<4;j++) pk4[j] = (bf16)(acc[m][n][j] + bv);
        *(bf16x4*)&out0[(size_t)(((bb*H_ + hh)*8 + kt)*4096) + c*8 + h8*4] = pk4;
      }
    }
  } else {
    #pragma unroll
    for (int m=0;m<4;m++){
      #pragma unroll
      for (int j=0;j<4;j++){
        size_t row = (size_t)m0 + wm*64 + m*16 + lg*4 + j;
        #pragma unroll
        for (int n=0;n<4;n++){
          int col = n0 + wn*64 + n*16 + lr;
          size_t idx = row*D_ + col;
          outf[idx] = acc[m][n][j] + bias0[col] + (float)res[idx];
        }
      }
    }
  }
}

// ---------------- Flash attention: 256 q-rows/block, 8 waves, dbuf-2 KV ------
// K: [b][s][h][dh]; VF: fragment-image. Grid (2,16,32), 512 thr. Zero-shuffle PV.
__global__ __launch_bounds__(512) void attn_fwd(
    const bf16* __restrict__ Q, const bf16* __restrict__ K,
    const bf16* __restrict__ VF, const int* __restrict__ mask,
    bf16* __restrict__ ctx)
{
  int flat = blockIdx.x + (blockIdx.y<<1) + (blockIdx.z<<5);   // 1024 wgs
  int work = (flat & 7)*128 + (flat >> 3);                     // bijective (1024%8==0)
  int qt = work & 1, h = (work>>1) & 15, b = work >> 5;
  int q0 = qt*256;
  int t = threadIdx.x, w = t>>6, l = t&63, lr = l&15, lg = (l>>4)&3;

  __shared__ bf16 K_s[2][4096];
  __shared__ bf16 V_s[2][4096];
  __shared__ float msk[512];

  const float SC = 0.125f * 1.44269504f;
  msk[t] = mask[b*S_+t] ? 0.f : -1.44269504e9f;

  size_t qbase  = ((size_t)(b*S_ + q0)*H_ + h)*DH_;
  size_t vfbase = (size_t)(b*H_ + h)*8*4096;

  auto stageKV = [&](int slot, int kt){
    size_t kb = ((size_t)(b*S_ + kt*64)*H_ + h)*DH_;
    int clr=t&15, clg=(t>>4)&3, ckk=(t>>6)&1, n16=t>>7;   // t = 0..511 chunks
    async16(K + kb + (size_t)(n16*16+clr)*D_ + ckk*32 + clg*8, &K_s[slot][t*8]);
    async16(VF + vfbase + (size_t)kt*4096 + t*8, &V_s[slot][t*8]);  // linear!
  };

  // Q straight to registers; wave w owns q rows w*32 .. w*32+31
  bf16x8 qa[2][2];
  #pragma unroll
  for (int s=0;s<2;s++)
    #pragma unroll
    for (int kk=0;kk<2;kk++)
      qa[s][kk] = *(const bf16x8*)(Q + qbase + (size_t)(w*32 + s*16 + lr)*D_ + kk*32 + lg*8);

  stageKV(0, 0);
  stageKV(1, 1);
  asm volatile("s_waitcnt vmcnt(2) lgkmcnt(0)" ::: "memory"); // Q + tile0 done, tile1 in flight
  __builtin_amdgcn_s_barrier();

  f32x4 cacc[2][4];
  #pragma unroll
  for (int s=0;s<2;s++)
    #pragma unroll
    for (int n=0;n<4;n++) cacc[s][n] = (f32x4){0.f,0.f,0.f,0.f};
  float mrun[2] = {-3.0e38f, -3.0e38f};
  float lrun[2] = {0.f, 0.f};

  union UPA { unsigned u[4]; bf16x8 v; };
  UPA pa[2][2];

  for (int kt=0; kt<8; ++kt) {
    int cur = kt & 1;
    const bf16* Ks = K_s[cur];
    const bf16* Vs = V_s[cur];

    // K fragments read ONCE, feed both q-subtiles
    bf16x8 kf[4][2];
    #pragma unroll
    for (int n=0;n<4;n++)
      #pragma unroll
      for (int kk=0;kk<2;kk++)
        kf[n][kk] = *(const bf16x8*)&Ks[(((n*2+kk)*4+lg)*16+lr)*8];

    #pragma unroll
    for (int s=0;s<2;s++){
      float p[4][4];
      #pragma unroll
      for (int n=0;n<4;n++){
        f32x4 sa = (f32x4){0.f,0.f,0.f,0.f};
        #pragma unroll
        for (int kk=0;kk<2;kk++)
          sa = __builtin_amdgcn_mfma_f32_16x16x32_bf16(kf[n][kk], qa[s][kk], sa, 0,0,0);
        float4 mk = *(const float4*)&msk[kt*64 + n*16 + lg*4];
        p[n][0] = sa[0]*SC + mk.x;
        p[n][1] = sa[1]*SC + mk.y;
        p[n][2] = sa[2]*SC + mk.z;
        p[n][3] = sa[3]*SC + mk.w;
      }

      float pm = fmaxf(fmaxf(p[0][0],p[0][1]),fmaxf(p[0][2],p[0][3]));
      #pragma unroll
      for (int n=1;n<4;n++)
        pm = fmaxf(pm, fmaxf(fmaxf(p[n][0],p[n][1]),fmaxf(p[n][2],p[n][3])));
      pm = fmaxf(pm, __shfl_xor(pm, 16, 64));
      pm = fmaxf(pm, __shfl_xor(pm, 32, 64));

      if (__any((int)(pm - mrun[s] > 8.f))) {          // T13 defer-max
        float mnew  = fmaxf(mrun[s], pm);
        float alpha = FEXP2(mrun[s] - mnew);
        mrun[s] = mnew;
        lrun[s] *= alpha;
        #pragma unroll
        for (int n=0;n<4;n++) cacc[s][n] *= alpha;
      }
      float ps = 0.f;
      #pragma unroll
      for (int n=0;n<4;n++)
        #pragma unroll
        for (int j=0;j<4;j++){ p[n][j] = FEXP2(p[n][j] - mrun[s]); ps += p[n][j]; }
      ps += __shfl_xor(ps, 16, 64);
      ps += __shfl_xor(ps, 32, 64);
      lrun[s] += ps;

      // pack P -> bf16 pairs; pa = in-lane rename (NO shuffles)
      unsigned pk[4][2];
      #pragma unroll
      for (int n=0;n<4;n++)
        #pragma unroll
        for (int i=0;i<2;i++){
          union { bf16x2 v; unsigned u; } u2;
          u2.v[0] = (bf16)p[n][2*i];
          u2.v[1] = (bf16)p[n][2*i+1];
          pk[n][i] = u2.u;
        }
      #pragma unroll
      for (int kk=0;kk<2;kk++){
        pa[s][kk].u[0] = pk[2*kk  ][0];
        pa[s][kk].u[1] = pk[2*kk  ][1];
        pa[s][kk].u[2] = pk[2*kk+1][0];
        pa[s][kk].u[3] = pk[2*kk+1][1];
      }
    }

    // PV: V fragments read inline from slot cur (before the recycle barrier)
    __builtin_amdgcn_s_setprio(1);
    #pragma unroll
    for (int nd=0;nd<4;nd++){
      bf16x8 vb0 = *(const bf16x8*)&Vs[(((nd*2+0)*4+lg)*16+lr)*8];
      bf16x8 vb1 = *(const bf16x8*)&Vs[(((nd*2+1)*4+lg)*16+lr)*8];
      #pragma unroll
      for (int s=0;s<2;s++){
        cacc[s][nd] = __builtin_amdgcn_mfma_f32_16x16x32_bf16(vb0, pa[s][0].v, cacc[s][nd], 0,0,0);
        cacc[s][nd] = __builtin_amdgcn_mfma_f32_16x16x32_bf16(vb1, pa[s][1].v, cacc[s][nd], 0,0,0);
      }
    }
    __builtin_amdgcn_s_setprio(0);

    asm volatile("s_waitcnt lgkmcnt(0)" ::: "memory");  // my reads of slot cur done
    __builtin_amdgcn_sched_barrier(0);
    __builtin_amdgcn_s_barrier();                       // ALL waves done with slot cur
    if (kt+2 < 8) stageKV(cur, kt+2);                   // recycle slot cur

    if (kt < 6)       asm volatile("s_waitcnt vmcnt(2)" ::: "memory");  // tile kt+1 landed
    else if (kt == 6) asm volatile("s_waitcnt vmcnt(0)" ::: "memory");
    if (kt < 7) { __builtin_amdgcn_sched_barrier(0); __builtin_amdgcn_s_barrier(); }
  }

  #pragma unroll
  for (int s=0;s<2;s++){
    float rl = 1.0f / lrun[s];
    size_t obase = qbase + (size_t)(w*32 + s*16 + lr)*D_;
    #pragma unroll
    for (int nd=0;nd<4;nd++){
      bf16x4 o4;
      #pragma unroll
      for (int j=0;j<4;j++) o4[j] = (bf16)(cacc[s][nd][j]*rl);
      *(bf16x4*)&ctx[obase + nd*16 + lg*4] = o4;
    }
  }
}

// ------------------------------ launcher --------------------------------------
extern "C" void kernel_launch(void* const* d_in, const int* in_sizes, int n_in,
                              void* d_out, int out_size, void* d_ws, size_t ws_size,
                              hipStream_t stream)
{
  (void)in_sizes; (void)n_in; (void)out_size; (void)ws_size;
  const float* qk   = (const float*)d_in[0];
  const float* v    = (const float*)d_in[1];
  const int*   mask = (const int*)  d_in[2];
  const float* qk_g = (const float*)d_in[3];
  const float* qk_b = (const float*)d_in[4];
  const float* v_g  = (const float*)d_in[5];
  const float* v_b  = (const float*)d_in[6];
  const float* Wq   = (const float*)d_in[7];
  const float* bq   = (const float*)d_in[8];
  const float* Wk   = (const float*)d_in[9];
  const float* bk   = (const float*)d_in[10];
  const float* Wv   = (const float*)d_in[11];
  const float* bv   = (const float*)d_in[12];
  const float* Wo   = (const float*)d_in[13];
  const float* bo   = (const float*)d_in[14];
  float* out = (float*)d_out;

  char* ws = (char*)d_ws;
  size_t off = 0;
  auto alloc = [&](size_t bytes){ void* p = ws + off; off += (bytes + 255) & ~(size_t)255; return p; };
  bf16* qkn  = (bf16*)alloc((size_t)M_*D_*2);
  bf16* vn   = (bf16*)alloc((size_t)M_*D_*2);
  bf16* Qb   = (bf16*)alloc((size_t)M_*D_*2);
  bf16* Kb   = (bf16*)alloc((size_t)M_*D_*2);
  bf16* VFb  = (bf16*)alloc((size_t)M_*D_*2);   // V fragment-image
  bf16* Cb   = (bf16*)alloc((size_t)M_*D_*2);
  bf16* WqkT = (bf16*)alloc((size_t)2*D_*D_*2);
  bf16* WvT  = (bf16*)alloc((size_t)D_*D_*2);
  bf16* WoT  = (bf16*)alloc((size_t)D_*D_*2);

  ln_bf16<<<2*M_, 256, 0, stream>>>(qk, v, qk_g, qk_b, v_g, v_b, qkn, vn);
  wtrans<<<dim3(32,32,4), dim3(32,8), 0, stream>>>(Wq, Wk, Wv, Wo,
      WqkT, WqkT + (size_t)D_*D_, WvT, WoT);
  gemm_bt<0><<<dim3(16,128), 256, 0, stream>>>(qkn, WqkT, bq, bk, nullptr, Qb, Kb, nullptr);
  gemm_bt<1><<<dim3(8,128),  256, 0, stream>>>(vn,  WvT,  bv, nullptr, nullptr, VFb, nullptr, nullptr);
  attn_fwd<<<dim3(2, 16, 32), 512, 0, stream>>>(Qb, Kb, VFb, mask, Cb);
  gemm_bt<2><<<dim3(8,128),  256, 0, stream>>>(Cb, WoT, bo, nullptr, vn, nullptr, nullptr, out);
}